// Round 8
// baseline (420.476 us; speedup 1.0000x reference)
//
#include <hip/hip_runtime.h>
#include <hip/hip_bf16.h>

#define NN 100000
#define EE 1600000
#define DD 128

#define BSH 9                       // 512 nodes per bucket
#define NBUK ((NN + 511) / 512)     // 196
#define EPB 8192                    // edges per block in partition kernels
#define PGRID ((EE + EPB - 1) / EPB)  // 196

typedef __attribute__((ext_vector_type(8))) _Float16 half8;
typedef __attribute__((ext_vector_type(4))) _Float16 half4;
typedef __attribute__((ext_vector_type(2))) _Float16 half2v;
typedef __attribute__((ext_vector_type(4))) float f32x4;

__device__ inline int detect64(const long long* __restrict__ ei64) {
    // sample first 64 int64 slots; valid window under either layout.
    long long v = ei64[threadIdx.x & 63];
    return __all(v >= 0 && v < (long long)NN);  // wave-uniform, same in all blocks
}

__device__ inline int load_edge(const int* ei32, const long long* ei64, int is64, size_t pos) {
    return is64 ? (int)ei64[pos] : ei32[pos];
}

// ---------------- bucket histogram: per-block rows, no global atomics ----------------
__global__ __launch_bounds__(1024) void k_bhist(const int* __restrict__ ei32,
                                                const long long* __restrict__ ei64,
                                                int* __restrict__ bh) {
    __shared__ int h[NBUK];
    int t = threadIdx.x;
    int is64 = detect64(ei64);
    if (t < NBUK) h[t] = 0;
    __syncthreads();
    int base = blockIdx.x * EPB;
    int end = min(base + EPB, EE);
    for (int e = base + t; e < end; e += 1024) {
        int d = load_edge(ei32, ei64, is64, (size_t)EE + e);
        atomicAdd(&h[d >> BSH], 1);
    }
    __syncthreads();
    if (t < NBUK) bh[blockIdx.x * 256 + t] = h[t];
}

// ---------------- scan: sum per-block rows, exclusive scan -> bbase/bcur ----------------
__global__ __launch_bounds__(256) void k_bscan(const int* __restrict__ bh,
                                               int* __restrict__ bbase,
                                               int* __restrict__ bcur) {
    __shared__ int sm[256];
    int t = threadIdx.x;
    int v = 0;
    if (t < NBUK)
        for (int b = 0; b < PGRID; ++b) v += bh[b * 256 + t];
    sm[t] = v;
    __syncthreads();
    for (int off = 1; off < 256; off <<= 1) {
        int u = (t >= off) ? sm[t - off] : 0;
        __syncthreads();
        sm[t] += u;
        __syncthreads();
    }
    if (t < NBUK) {
        int b = sm[t] - v;
        bbase[t] = b;
        bcur[t] = b;
    }
    if (t == 0) bbase[NBUK] = EE;
}

// ---------------- partition edges into bucket-contiguous staging ----------------
// two-pass (reload edges) -> no dynamically-indexed private arrays, no scratch
__global__ __launch_bounds__(1024) void k_part(const int* __restrict__ ei32,
                                               const long long* __restrict__ ei64,
                                               int* __restrict__ bcur,
                                               unsigned* __restrict__ eb) {
    __shared__ int h[NBUK];
    __shared__ int cbase[NBUK];
    int t = threadIdx.x;
    int is64 = detect64(ei64);
    if (t < NBUK) h[t] = 0;
    __syncthreads();
    int base = blockIdx.x * EPB;
    int end = min(base + EPB, EE);
    for (int e = base + t; e < end; e += 1024) {
        int d = load_edge(ei32, ei64, is64, (size_t)EE + e);
        atomicAdd(&h[d >> BSH], 1);
    }
    __syncthreads();
    if (t < NBUK && h[t] > 0) cbase[t] = atomicAdd(&bcur[t], h[t]);
    __syncthreads();
    if (t < NBUK) h[t] = 0;   // reuse as local cursor
    __syncthreads();
    for (int e = base + t; e < end; e += 1024) {
        int s = load_edge(ei32, ei64, is64, (size_t)e);
        int d = load_edge(ei32, ei64, is64, (size_t)EE + e);
        int b = d >> BSH;
        int slot = atomicAdd(&h[b], 1);
        eb[cbase[b] + slot] = (unsigned)s | ((unsigned)(d & 511) << 17);
    }
}

// ---------------- per-bucket counting sort: one block per bucket ----------------
__global__ __launch_bounds__(1024) void k_bucket(const unsigned* __restrict__ eb,
                                                 const int* __restrict__ bbase,
                                                 int* __restrict__ rp,
                                                 int* __restrict__ ssrc) {
    __shared__ int ncnt[512];
    __shared__ int cur[512];
    int b = blockIdx.x, t = threadIdx.x;
    int ebeg = bbase[b], eend = bbase[b + 1];
    int nodeBase = b << BSH;
    int nNodes = min(512, NN - nodeBase);
    if (t < 512) ncnt[t] = 0;
    __syncthreads();
    for (int i = ebeg + t; i < eend; i += 1024) {
        unsigned v = eb[i];
        atomicAdd(&ncnt[v >> 17], 1);
    }
    __syncthreads();
    int own = (t < 512) ? ncnt[t] : 0;
    for (int off = 1; off < 512; off <<= 1) {
        int u = (t >= off && t < 512) ? ncnt[t - off] : 0;
        __syncthreads();
        if (t < 512) ncnt[t] += u;
        __syncthreads();
    }
    if (t < 512) {
        int excl = ncnt[t] - own;
        cur[t] = ebeg + excl;
        if (t < nNodes) rp[nodeBase + t] = ebeg + excl;
    }
    __syncthreads();
    for (int i = ebeg + t; i < eend; i += 1024) {
        unsigned v = eb[i];
        int slot = atomicAdd(&cur[v >> 17], 1);
        ssrc[slot] = (int)(v & 0x1FFFFu);
    }
    if (b == 0 && t == 0) rp[NN] = EE;
}

// ---------------- GEMM: out = relu(A@W1.T [+ A2@W2.T] + bias) ----------------
// W staged f32->fp16 into LDS (stride 136: 16B-aligned reads, 2-way banks = free).
// fp16 A: 1 MFMA/tile. f32 A: f16 hi/lo split of A, 2 MFMAs/tile.
#define WSTR 136

__device__ inline void stageW(const float* __restrict__ Wg, _Float16* sW, int t) {
#pragma unroll
    for (int i = 0; i < 16; ++i) {
        int c = t + i * 256;          // 4096 float4 chunks of the 128x128 matrix
        int n = c >> 5, j = c & 31;
        float4 w = ((const float4*)Wg)[c];
        half4 o;
        o[0] = (_Float16)w.x; o[1] = (_Float16)w.y;
        o[2] = (_Float16)w.z; o[3] = (_Float16)w.w;
        *(half4*)(sW + n * WSTR + j * 4) = o;
    }
}

template <bool DUAL, bool AF16, bool OF16>
__global__ __launch_bounds__(256) void k_gemm(const void* __restrict__ A,
                                              const float* __restrict__ W1g,
                                              const void* __restrict__ A2,
                                              const float* __restrict__ W2g,
                                              const float* __restrict__ bias,
                                              void* __restrict__ out) {
    __shared__ _Float16 sW[128 * WSTR];
    int t = threadIdx.x;
    int wave = t >> 6;
    int lane = t & 63;
    int lr = lane & 15;
    int lk = lane >> 4;
    int rowBase = blockIdx.x * 128 + wave * 32;

    f32x4 acc[2][8];
#pragma unroll
    for (int mt = 0; mt < 2; ++mt)
#pragma unroll
        for (int nt = 0; nt < 8; ++nt) acc[mt][nt] = (f32x4){0.f, 0.f, 0.f, 0.f};

    const int NPASS = DUAL ? 2 : 1;
    for (int pass = 0; pass < NPASS; ++pass) {
        const float* Wg = pass ? W2g : W1g;
        const void* Ap = pass ? A2 : A;
        if (pass) __syncthreads();             // protect LDS before overwrite
        stageW(Wg, sW, t);
        __syncthreads();

#pragma unroll
        for (int ks = 0; ks < 4; ++ks) {
            int kf = ks * 32 + lk * 8;
            half8 b[8];
#pragma unroll
            for (int nt = 0; nt < 8; ++nt)
                b[nt] = *(const half8*)(sW + (nt * 16 + lr) * WSTR + kf);
#pragma unroll
            for (int mt = 0; mt < 2; ++mt) {
                int row = rowBase + mt * 16 + lr;
                int rc = row < NN ? row : NN - 1;
                if (AF16) {
                    half8 a = *(const half8*)((const _Float16*)Ap + (size_t)rc * 128 + kf);
#pragma unroll
                    for (int nt = 0; nt < 8; ++nt)
                        acc[mt][nt] = __builtin_amdgcn_mfma_f32_16x16x32_f16(a, b[nt], acc[mt][nt], 0, 0, 0);
                } else {
                    const float* ap = (const float*)Ap + (size_t)rc * 128 + kf;
                    float4 a0 = *(const float4*)ap;
                    float4 a1 = *(const float4*)(ap + 4);
                    float av[8] = {a0.x, a0.y, a0.z, a0.w, a1.x, a1.y, a1.z, a1.w};
                    half8 ah, al;
#pragma unroll
                    for (int j = 0; j < 8; ++j) {
                        _Float16 h = (_Float16)av[j];
                        ah[j] = h;
                        al[j] = (_Float16)(av[j] - (float)h);
                    }
#pragma unroll
                    for (int nt = 0; nt < 8; ++nt) {
                        acc[mt][nt] = __builtin_amdgcn_mfma_f32_16x16x32_f16(ah, b[nt], acc[mt][nt], 0, 0, 0);
                        acc[mt][nt] = __builtin_amdgcn_mfma_f32_16x16x32_f16(al, b[nt], acc[mt][nt], 0, 0, 0);
                    }
                }
            }
        }
    }

    // epilogue: C/D layout col=lane&15, row=(lane>>4)*4+reg  [verified mapping]
#pragma unroll
    for (int mt = 0; mt < 2; ++mt) {
#pragma unroll
        for (int nt = 0; nt < 8; ++nt) {
            int col = nt * 16 + lr;
            float b = bias[col];
#pragma unroll
            for (int r = 0; r < 4; ++r) {
                int row = rowBase + mt * 16 + lk * 4 + r;
                if (row < NN) {
                    float v = acc[mt][nt][r] + b;
                    v = v > 0.f ? v : 0.f;
                    if (OF16)
                        ((_Float16*)out)[(size_t)row * 128 + col] = (_Float16)v;
                    else
                        ((float*)out)[(size_t)row * 128 + col] = v;
                }
            }
        }
    }
}

// ---------------- mean aggregation: wave per node, 4 rows per wave-load ----------------
// lane = g*16+f; packed-fp16 pairwise adds (2-term fp16 sums only), fp32 accumulate.
// Unmasked fast path for full 16-edge iterations; masked path only on the tail.
__global__ __launch_bounds__(256) void k_agg(const _Float16* __restrict__ h,
                                             const int* __restrict__ rp,
                                             const int* __restrict__ ssrc,
                                             _Float16* __restrict__ out) {
    int wid = (int)((blockIdx.x * 256 + threadIdx.x) >> 6);
    int lane = threadIdx.x & 63;
    if (wid >= NN) return;
    int g = lane >> 4;
    int f = lane & 15;
    int s = __builtin_amdgcn_readfirstlane(rp[wid]);
    int e = __builtin_amdgcn_readfirstlane(rp[wid + 1]);
    int deg = e - s;

    const half2v ONE = {(_Float16)1.f, (_Float16)1.f};
    const half2v ZER = {(_Float16)0.f, (_Float16)0.f};
    float fa[8] = {0.f, 0.f, 0.f, 0.f, 0.f, 0.f, 0.f, 0.f};

    for (int j = s; j < e; j += 16) {
        int j0 = j + g, j1 = j + 4 + g, j2 = j + 8 + g, j3 = j + 12 + g;
        int r0 = ssrc[j0 < e ? j0 : s];
        int r1 = ssrc[j1 < e ? j1 : s];
        int r2 = ssrc[j2 < e ? j2 : s];
        int r3 = ssrc[j3 < e ? j3 : s];
        half8 v0 = *(const half8*)(h + (size_t)r0 * 128 + f * 8);
        half8 v1 = *(const half8*)(h + (size_t)r1 * 128 + f * 8);
        half8 v2 = *(const half8*)(h + (size_t)r2 * 128 + f * 8);
        half8 v3 = *(const half8*)(h + (size_t)r3 * 128 + f * 8);
        if (j + 16 <= e) {
#pragma unroll
            for (int q = 0; q < 4; ++q) {
                half2v p0 = {v0[2 * q], v0[2 * q + 1]};
                half2v p1 = {v1[2 * q], v1[2 * q + 1]};
                half2v p2 = {v2[2 * q], v2[2 * q + 1]};
                half2v p3 = {v3[2 * q], v3[2 * q + 1]};
                half2v sA = p0 + p1;        // v_pk_add_f16, 2-term fp16 sums only
                half2v sB = p2 + p3;
                fa[2 * q]     += (float)sA.x + (float)sB.x;
                fa[2 * q + 1] += (float)sA.y + (float)sB.y;
            }
        } else {
            half2v m0 = j0 < e ? ONE : ZER;
            half2v m1 = j1 < e ? ONE : ZER;
            half2v m2 = j2 < e ? ONE : ZER;
            half2v m3 = j3 < e ? ONE : ZER;
#pragma unroll
            for (int q = 0; q < 4; ++q) {
                half2v p0 = {v0[2 * q], v0[2 * q + 1]};
                half2v p1 = {v1[2 * q], v1[2 * q + 1]};
                half2v p2 = {v2[2 * q], v2[2 * q + 1]};
                half2v p3 = {v3[2 * q], v3[2 * q + 1]};
                half2v sA = p0 * m0 + p1 * m1;   // v_pk_mul + v_pk_fma
                half2v sB = p2 * m2 + p3 * m3;
                fa[2 * q]     += (float)sA.x + (float)sB.x;
                fa[2 * q + 1] += (float)sA.y + (float)sB.y;
            }
        }
    }
    // reduce across the 4 groups (lanes f, 16+f, 32+f, 48+f)
#pragma unroll
    for (int q = 0; q < 8; ++q) {
        fa[q] += __shfl_xor(fa[q], 16, 64);
        fa[q] += __shfl_xor(fa[q], 32, 64);
    }
    float inv = deg > 0 ? 1.0f / (float)deg : 0.f;
    if (g == 0) {
        half8 o;
#pragma unroll
        for (int q = 0; q < 8; ++q) o[q] = (_Float16)(fa[q] * inv);
        *(half8*)(out + (size_t)wid * 128 + f * 8) = o;
    }
}

// ---------------- launch ----------------
extern "C" void kernel_launch(void* const* d_in, const int* in_sizes, int n_in,
                              void* d_out, int out_size, void* d_ws, size_t ws_size,
                              hipStream_t stream) {
    const float* x = (const float*)d_in[0];
    const int* ei32 = (const int*)d_in[1];
    const long long* ei64 = (const long long*)d_in[1];
    const float* W1 = (const float*)d_in[2];
    const float* b1 = (const float*)d_in[3];
    const float* W2 = (const float*)d_in[4];
    const float* b2 = (const float*)d_in[5];
    const float* c1Wl = (const float*)d_in[6];
    const float* c1_bl = (const float*)d_in[7];
    const float* c1Wr = (const float*)d_in[8];
    const float* c2Wl = (const float*)d_in[9];
    const float* c2_bl = (const float*)d_in[10];
    const float* c2Wr = (const float*)d_in[11];

    char* ws = (char*)d_ws;
    const size_t H16 = (size_t)NN * 128 * 2;     // 25,600,000
    _Float16* hH = (_Float16*)ws;                // fp16 node table
    _Float16* aggH = (_Float16*)(ws + H16);      // fp16 mean / h2 table
    int* ssrc = (int*)(ws + 2 * H16);            // E ints
    int* rp = (int*)(ws + 2 * H16 + 6400000);    // N+1 (padded 400128)
    int* bh = (int*)(ws + 2 * H16 + 6400000 + 400128);   // PGRID*256 ints
    int* bbase = bh + PGRID * 256;               // NBUK+1
    int* bcur = bbase + 256;                     // NBUK
    unsigned* eb = (unsigned*)hH;                // E staged edges (hH written later)

    k_bhist<<<PGRID, 1024, 0, stream>>>(ei32, ei64, bh);
    k_bscan<<<1, 256, 0, stream>>>(bh, bbase, bcur);
    k_part<<<PGRID, 1024, 0, stream>>>(ei32, ei64, bcur, eb);
    k_bucket<<<NBUK, 1024, 0, stream>>>(eb, bbase, rp, ssrc);

    dim3 g((NN + 127) / 128);
    int agrid = (NN + 3) / 4;
    // h1 = relu(x@W1.T+b1) -> fp16 hH
    k_gemm<false, false, true><<<g, 256, 0, stream>>>(x, W1, nullptr, nullptr, b1, hH);
    // conv1: mean-agg then dual GEMM, fp16 output in-place over aggH
    k_agg<<<agrid, 256, 0, stream>>>(hH, rp, ssrc, aggH);
    k_gemm<true, true, true><<<g, 256, 0, stream>>>(aggH, c1Wl, hH, c1Wr, c1_bl, aggH);
    // h3 = relu(h2@W2.T+b2) -> fp16 hH
    k_gemm<false, true, true><<<g, 256, 0, stream>>>(aggH, W2, nullptr, nullptr, b2, hH);
    // conv2 -> f32 d_out
    k_agg<<<agrid, 256, 0, stream>>>(hH, rp, ssrc, aggH);
    k_gemm<true, true, false><<<g, 256, 0, stream>>>(aggH, c2Wl, hH, c2Wr, c2_bl, d_out);
}

// Round 9
// 367.458 us; speedup vs baseline: 1.1443x; 1.1443x over previous
//
#include <hip/hip_runtime.h>
#include <hip/hip_bf16.h>

#define NN 100000
#define EE 1600000
#define DD 128

#define BSH 9                       // 512 nodes per bucket
#define NBUK ((NN + 511) / 512)     // 196
#define EPB 8192                    // edges per block in partition kernels
#define PGRID ((EE + EPB - 1) / EPB)  // 196

typedef __attribute__((ext_vector_type(8))) _Float16 half8;
typedef __attribute__((ext_vector_type(2))) _Float16 half2v;
typedef __attribute__((ext_vector_type(4))) float f32x4;

__device__ inline int detect64(const long long* __restrict__ ei64) {
    // sample first 64 int64 slots; window valid under either layout.
    long long v = ei64[threadIdx.x & 63];
    return __all(v >= 0 && v < (long long)NN);  // same verdict in every wave
}

__device__ inline int load_edge(const int* ei32, const long long* ei64, int is64, size_t pos) {
    return is64 ? (int)ei64[pos] : ei32[pos];
}

// ---------------- bucket histogram (196 buckets of 512 dst nodes) ----------------
__global__ __launch_bounds__(1024) void k_bhist(const int* __restrict__ ei32,
                                                const long long* __restrict__ ei64,
                                                int* __restrict__ bcnt) {
    __shared__ int h[NBUK];
    int t = threadIdx.x;
    int is64 = detect64(ei64);
    if (t < NBUK) h[t] = 0;
    __syncthreads();
    int base = blockIdx.x * EPB;
    int end = min(base + EPB, EE);
    for (int e = base + t; e < end; e += 1024) {
        int d = load_edge(ei32, ei64, is64, (size_t)EE + e);
        atomicAdd(&h[d >> BSH], 1);
    }
    __syncthreads();
    if (t < NBUK && h[t] > 0) atomicAdd(&bcnt[t], h[t]);
}

__global__ __launch_bounds__(256) void k_bscan(const int* __restrict__ bcnt,
                                               int* __restrict__ bbase,
                                               int* __restrict__ bcur) {
    __shared__ int sm[256];
    int t = threadIdx.x;
    int v = (t < NBUK) ? bcnt[t] : 0;
    sm[t] = v;
    __syncthreads();
    for (int off = 1; off < 256; off <<= 1) {
        int u = (t >= off) ? sm[t - off] : 0;
        __syncthreads();
        sm[t] += u;
        __syncthreads();
    }
    if (t < NBUK) {
        int b = sm[t] - v;
        bbase[t] = b;
        bcur[t] = b;
    }
    if (t == 0) bbase[NBUK] = EE;
}

// ---------------- partition edges into bucket-contiguous staging ----------------
// two-pass (reload edges) -> no dynamically-indexed private arrays
__global__ __launch_bounds__(1024) void k_part(const int* __restrict__ ei32,
                                               const long long* __restrict__ ei64,
                                               int* __restrict__ bcur,
                                               unsigned* __restrict__ eb) {
    __shared__ int h[NBUK];
    __shared__ int cbase[NBUK];
    int t = threadIdx.x;
    int is64 = detect64(ei64);
    if (t < NBUK) h[t] = 0;
    __syncthreads();
    int base = blockIdx.x * EPB;
    int end = min(base + EPB, EE);
    for (int e = base + t; e < end; e += 1024) {
        int d = load_edge(ei32, ei64, is64, (size_t)EE + e);
        atomicAdd(&h[d >> BSH], 1);
    }
    __syncthreads();
    if (t < NBUK && h[t] > 0) cbase[t] = atomicAdd(&bcur[t], h[t]);
    __syncthreads();
    if (t < NBUK) h[t] = 0;   // reuse as local cursor
    __syncthreads();
    for (int e = base + t; e < end; e += 1024) {
        int s = load_edge(ei32, ei64, is64, (size_t)e);
        int d = load_edge(ei32, ei64, is64, (size_t)EE + e);
        int b = d >> BSH;
        int slot = atomicAdd(&h[b], 1);
        eb[cbase[b] + slot] = (unsigned)s | ((unsigned)(d & 511) << 17);
    }
}

// ---------------- per-bucket counting sort: one block per bucket ----------------
__global__ __launch_bounds__(1024) void k_bucket(const unsigned* __restrict__ eb,
                                                 const int* __restrict__ bbase,
                                                 int* __restrict__ rp,
                                                 int* __restrict__ ssrc) {
    __shared__ int ncnt[512];
    __shared__ int cur[512];
    int b = blockIdx.x, t = threadIdx.x;
    int ebeg = bbase[b], eend = bbase[b + 1];
    int nodeBase = b << BSH;
    int nNodes = min(512, NN - nodeBase);
    if (t < 512) ncnt[t] = 0;
    __syncthreads();
    for (int i = ebeg + t; i < eend; i += 1024) {
        unsigned v = eb[i];
        atomicAdd(&ncnt[v >> 17], 1);
    }
    __syncthreads();
    int own = (t < 512) ? ncnt[t] : 0;
    for (int off = 1; off < 512; off <<= 1) {
        int u = (t >= off && t < 512) ? ncnt[t - off] : 0;
        __syncthreads();
        if (t < 512) ncnt[t] += u;
        __syncthreads();
    }
    if (t < 512) {
        int excl = ncnt[t] - own;
        cur[t] = ebeg + excl;
        if (t < nNodes) rp[nodeBase + t] = ebeg + excl;
    }
    __syncthreads();
    for (int i = ebeg + t; i < eend; i += 1024) {
        unsigned v = eb[i];
        int slot = atomicAdd(&cur[v >> 17], 1);
        ssrc[slot] = (int)(v & 0x1FFFFu);
    }
    if (b == 0 && t == 0) rp[NN] = EE;
}

// ---------------- weight prep: f32 -> fp16, once ----------------
__global__ void k_prepw(const float* __restrict__ w0, const float* __restrict__ w1,
                        const float* __restrict__ w2, const float* __restrict__ w3,
                        const float* __restrict__ w4, const float* __restrict__ w5,
                        _Float16* __restrict__ whi) {
    int i = blockIdx.x * 256 + threadIdx.x;     // 6 * 16384
    if (i >= 6 * 16384) return;
    int slot = i >> 14, idx = i & 16383;
    const float* w = slot == 0 ? w0 : slot == 1 ? w1 : slot == 2 ? w2
                   : slot == 3 ? w3 : slot == 4 ? w4 : w5;
    whi[i] = (_Float16)w[idx];
}

// ---------------- shared GEMM helpers ----------------
#define WSTR 136   // LDS row stride (halves): 272B, 16B-aligned, conflict-free in practice

__device__ inline void stageW16(const _Float16* __restrict__ Wg, _Float16* sW, int t) {
#pragma unroll
    for (int i = 0; i < 8; ++i) {
        int c = t + i * 256;          // 2048 16B chunks
        int n = c >> 4, j = c & 15;
        *(half8*)(sW + n * WSTR + j * 8) = *(const half8*)(Wg + n * 128 + j * 8);
    }
}

// ---------------- GEMM: out = relu(A@W1.T [+ A2@W2.T] + bias) ----------------
template <bool DUAL, bool AF16, bool OF16>
__global__ __launch_bounds__(256) void k_gemm(const void* __restrict__ A,
                                              const _Float16* __restrict__ W1g,
                                              const void* __restrict__ A2,
                                              const _Float16* __restrict__ W2g,
                                              const float* __restrict__ bias,
                                              void* __restrict__ out) {
    __shared__ _Float16 sW[128 * WSTR];
    int t = threadIdx.x;
    int wave = t >> 6;
    int lane = t & 63;
    int lr = lane & 15;
    int lk = lane >> 4;
    int rowBase = blockIdx.x * 128 + wave * 32;

    f32x4 acc[2][8];
#pragma unroll
    for (int mt = 0; mt < 2; ++mt)
#pragma unroll
        for (int nt = 0; nt < 8; ++nt) acc[mt][nt] = (f32x4){0.f, 0.f, 0.f, 0.f};

    const int NPASS = DUAL ? 2 : 1;
    for (int pass = 0; pass < NPASS; ++pass) {
        const _Float16* Wg = pass ? W2g : W1g;
        const void* Ap = pass ? A2 : A;
        if (pass) __syncthreads();             // protect LDS before overwrite
        stageW16(Wg, sW, t);
        __syncthreads();

#pragma unroll
        for (int ks = 0; ks < 4; ++ks) {
            int kf = ks * 32 + lk * 8;
            half8 b[8];
#pragma unroll
            for (int nt = 0; nt < 8; ++nt)
                b[nt] = *(const half8*)(sW + (nt * 16 + lr) * WSTR + kf);
#pragma unroll
            for (int mt = 0; mt < 2; ++mt) {
                int row = rowBase + mt * 16 + lr;
                int rc = row < NN ? row : NN - 1;
                if (AF16) {
                    half8 a = *(const half8*)((const _Float16*)Ap + (size_t)rc * 128 + kf);
#pragma unroll
                    for (int nt = 0; nt < 8; ++nt)
                        acc[mt][nt] = __builtin_amdgcn_mfma_f32_16x16x32_f16(a, b[nt], acc[mt][nt], 0, 0, 0);
                } else {
                    const float* ap = (const float*)Ap + (size_t)rc * 128 + kf;
                    float4 a0 = *(const float4*)ap;
                    float4 a1 = *(const float4*)(ap + 4);
                    float av[8] = {a0.x, a0.y, a0.z, a0.w, a1.x, a1.y, a1.z, a1.w};
                    half8 ah, al;
#pragma unroll
                    for (int j = 0; j < 8; ++j) {
                        _Float16 h = (_Float16)av[j];
                        ah[j] = h;
                        al[j] = (_Float16)(av[j] - (float)h);
                    }
#pragma unroll
                    for (int nt = 0; nt < 8; ++nt) {
                        acc[mt][nt] = __builtin_amdgcn_mfma_f32_16x16x32_f16(ah, b[nt], acc[mt][nt], 0, 0, 0);
                        acc[mt][nt] = __builtin_amdgcn_mfma_f32_16x16x32_f16(al, b[nt], acc[mt][nt], 0, 0, 0);
                    }
                }
            }
        }
    }

    // epilogue: C/D layout col=lane&15, row=(lane>>4)*4+reg
#pragma unroll
    for (int mt = 0; mt < 2; ++mt) {
#pragma unroll
        for (int nt = 0; nt < 8; ++nt) {
            int col = nt * 16 + lr;
            float b = bias[col];
#pragma unroll
            for (int r = 0; r < 4; ++r) {
                int row = rowBase + mt * 16 + lk * 4 + r;
                if (row < NN) {
                    float v = acc[mt][nt][r] + b;
                    v = v > 0.f ? v : 0.f;
                    if (OF16)
                        ((_Float16*)out)[(size_t)row * 128 + col] = (_Float16)v;
                    else
                        ((float*)out)[(size_t)row * 128 + col] = v;
                }
            }
        }
    }
}

// ---------------- fused conv1 + lin2: h3 = relu(relu(agg@Wl + root@Wr + bc)@Wlin + bl)
// No gather inside (agg pre-materialized): all loads streaming. h2 transits LDS only.
// In-place out==aggH is safe: each block reads only its own rows before writing them.
__global__ __launch_bounds__(256) void k_cfuse(const _Float16* __restrict__ aggH,
                                               const _Float16* __restrict__ rootH,
                                               const _Float16* __restrict__ Wlg,
                                               const _Float16* __restrict__ Wrg,
                                               const float* __restrict__ bconv,
                                               const _Float16* __restrict__ Wling,
                                               const float* __restrict__ blin,
                                               _Float16* __restrict__ out) {
    __shared__ _Float16 sW[128 * WSTR];
    __shared__ _Float16 sA[128 * WSTR];
    int t = threadIdx.x;
    int wave = t >> 6, lane = t & 63;
    int lr = lane & 15, lk = lane >> 4;
    int rowBase = blockIdx.x * 128 + wave * 32;

    f32x4 acc[2][8];
#pragma unroll
    for (int mt = 0; mt < 2; ++mt)
#pragma unroll
        for (int nt = 0; nt < 8; ++nt) acc[mt][nt] = (f32x4){0.f, 0.f, 0.f, 0.f};

    // pass 1: agg @ Wl
    stageW16(Wlg, sW, t);
    __syncthreads();
#pragma unroll
    for (int ks = 0; ks < 4; ++ks) {
        int kf = ks * 32 + lk * 8;
        half8 b[8];
#pragma unroll
        for (int nt = 0; nt < 8; ++nt)
            b[nt] = *(const half8*)(sW + (nt * 16 + lr) * WSTR + kf);
#pragma unroll
        for (int mt = 0; mt < 2; ++mt) {
            int row = rowBase + mt * 16 + lr;
            int rc = row < NN ? row : NN - 1;
            half8 a = *(const half8*)(aggH + (size_t)rc * 128 + kf);
#pragma unroll
            for (int nt = 0; nt < 8; ++nt)
                acc[mt][nt] = __builtin_amdgcn_mfma_f32_16x16x32_f16(a, b[nt], acc[mt][nt], 0, 0, 0);
        }
    }
    __syncthreads();

    // pass 2: root @ Wr
    stageW16(Wrg, sW, t);
    __syncthreads();
#pragma unroll
    for (int ks = 0; ks < 4; ++ks) {
        int kf = ks * 32 + lk * 8;
        half8 b[8];
#pragma unroll
        for (int nt = 0; nt < 8; ++nt)
            b[nt] = *(const half8*)(sW + (nt * 16 + lr) * WSTR + kf);
#pragma unroll
        for (int mt = 0; mt < 2; ++mt) {
            int row = rowBase + mt * 16 + lr;
            int rc = row < NN ? row : NN - 1;
            half8 a = *(const half8*)(rootH + (size_t)rc * 128 + kf);
#pragma unroll
            for (int nt = 0; nt < 8; ++nt)
                acc[mt][nt] = __builtin_amdgcn_mfma_f32_16x16x32_f16(a, b[nt], acc[mt][nt], 0, 0, 0);
        }
    }

    // h2 = relu(acc + bconv) -> own LDS rows (C-layout scatter)
#pragma unroll
    for (int mt = 0; mt < 2; ++mt)
#pragma unroll
        for (int nt = 0; nt < 8; ++nt) {
            int col = nt * 16 + lr;
            float bia = bconv[col];
#pragma unroll
            for (int r = 0; r < 4; ++r) {
                float v = acc[mt][nt][r] + bia;
                sA[(wave * 32 + mt * 16 + lk * 4 + r) * WSTR + col] = (_Float16)(v > 0.f ? v : 0.f);
            }
        }
    __syncthreads();           // sA complete, sW reads of pass 2 done

    // pass 3: h2 (LDS) @ Wlin
    stageW16(Wling, sW, t);
    __syncthreads();
#pragma unroll
    for (int mt = 0; mt < 2; ++mt)
#pragma unroll
        for (int nt = 0; nt < 8; ++nt) acc[mt][nt] = (f32x4){0.f, 0.f, 0.f, 0.f};
#pragma unroll
    for (int ks = 0; ks < 4; ++ks) {
        int kf = ks * 32 + lk * 8;
        half8 b[8];
#pragma unroll
        for (int nt = 0; nt < 8; ++nt)
            b[nt] = *(const half8*)(sW + (nt * 16 + lr) * WSTR + kf);
#pragma unroll
        for (int mt = 0; mt < 2; ++mt) {
            half8 a = *(const half8*)(sA + (wave * 32 + mt * 16 + lr) * WSTR + kf);
#pragma unroll
            for (int nt = 0; nt < 8; ++nt)
                acc[mt][nt] = __builtin_amdgcn_mfma_f32_16x16x32_f16(a, b[nt], acc[mt][nt], 0, 0, 0);
        }
    }

#pragma unroll
    for (int mt = 0; mt < 2; ++mt)
#pragma unroll
        for (int nt = 0; nt < 8; ++nt) {
            int col = nt * 16 + lr;
            float bia = blin[col];
#pragma unroll
            for (int r = 0; r < 4; ++r) {
                int row = rowBase + mt * 16 + lk * 4 + r;
                if (row < NN) {
                    float v = acc[mt][nt][r] + bia;
                    out[(size_t)row * 128 + col] = (_Float16)(v > 0.f ? v : 0.f);
                }
            }
        }
}

// ---------------- mean aggregation: wave per node, 4 rows per wave-load ----------------
__global__ __launch_bounds__(256) void k_agg(const _Float16* __restrict__ h,
                                             const int* __restrict__ rp,
                                             const int* __restrict__ ssrc,
                                             _Float16* __restrict__ out) {
    int wid = (int)((blockIdx.x * 256 + threadIdx.x) >> 6);
    int lane = threadIdx.x & 63;
    if (wid >= NN) return;
    int g = lane >> 4;
    int f = lane & 15;
    int s = __builtin_amdgcn_readfirstlane(rp[wid]);
    int e = __builtin_amdgcn_readfirstlane(rp[wid + 1]);
    int deg = e - s;

    const half2v ONE = {(_Float16)1.f, (_Float16)1.f};
    const half2v ZER = {(_Float16)0.f, (_Float16)0.f};
    float fa[8] = {0.f, 0.f, 0.f, 0.f, 0.f, 0.f, 0.f, 0.f};

    for (int j = s; j < e; j += 16) {
        int j0 = j + g, j1 = j + 4 + g, j2 = j + 8 + g, j3 = j + 12 + g;
        int r0 = ssrc[j0 < e ? j0 : s];
        int r1 = ssrc[j1 < e ? j1 : s];
        int r2 = ssrc[j2 < e ? j2 : s];
        int r3 = ssrc[j3 < e ? j3 : s];
        half8 v0 = *(const half8*)(h + (size_t)r0 * 128 + f * 8);
        half8 v1 = *(const half8*)(h + (size_t)r1 * 128 + f * 8);
        half8 v2 = *(const half8*)(h + (size_t)r2 * 128 + f * 8);
        half8 v3 = *(const half8*)(h + (size_t)r3 * 128 + f * 8);
        if (j + 16 <= e) {
#pragma unroll
            for (int q = 0; q < 4; ++q) {
                half2v p0 = {v0[2 * q], v0[2 * q + 1]};
                half2v p1 = {v1[2 * q], v1[2 * q + 1]};
                half2v p2 = {v2[2 * q], v2[2 * q + 1]};
                half2v p3 = {v3[2 * q], v3[2 * q + 1]};
                half2v sA2 = p0 + p1;
                half2v sB2 = p2 + p3;
                fa[2 * q]     += (float)sA2.x + (float)sB2.x;
                fa[2 * q + 1] += (float)sA2.y + (float)sB2.y;
            }
        } else {
            half2v m0 = j0 < e ? ONE : ZER;
            half2v m1 = j1 < e ? ONE : ZER;
            half2v m2 = j2 < e ? ONE : ZER;
            half2v m3 = j3 < e ? ONE : ZER;
#pragma unroll
            for (int q = 0; q < 4; ++q) {
                half2v p0 = {v0[2 * q], v0[2 * q + 1]};
                half2v p1 = {v1[2 * q], v1[2 * q + 1]};
                half2v p2 = {v2[2 * q], v2[2 * q + 1]};
                half2v p3 = {v3[2 * q], v3[2 * q + 1]};
                half2v sA2 = p0 * m0 + p1 * m1;
                half2v sB2 = p2 * m2 + p3 * m3;
                fa[2 * q]     += (float)sA2.x + (float)sB2.x;
                fa[2 * q + 1] += (float)sA2.y + (float)sB2.y;
            }
        }
    }
#pragma unroll
    for (int q = 0; q < 8; ++q) {
        fa[q] += __shfl_xor(fa[q], 16, 64);
        fa[q] += __shfl_xor(fa[q], 32, 64);
    }
    float inv = deg > 0 ? 1.0f / (float)deg : 0.f;
    if (g == 0) {
        half8 o;
#pragma unroll
        for (int q = 0; q < 8; ++q) o[q] = (_Float16)(fa[q] * inv);
        *(half8*)(out + (size_t)wid * 128 + f * 8) = o;
    }
}

// ---------------- launch ----------------
extern "C" void kernel_launch(void* const* d_in, const int* in_sizes, int n_in,
                              void* d_out, int out_size, void* d_ws, size_t ws_size,
                              hipStream_t stream) {
    const float* x = (const float*)d_in[0];
    const int* ei32 = (const int*)d_in[1];
    const long long* ei64 = (const long long*)d_in[1];
    const float* b1 = (const float*)d_in[3];
    const float* b2 = (const float*)d_in[5];
    const float* c1_bl = (const float*)d_in[7];
    const float* c2_bl = (const float*)d_in[10];

    char* ws = (char*)d_ws;
    const size_t H16 = (size_t)NN * 128 * 2;     // 25,600,000
    _Float16* hH = (_Float16*)ws;                // table A
    _Float16* aggH = (_Float16*)(ws + H16);      // table B
    int* ssrc = (int*)(ws + 2 * H16);            // E ints
    int* rp = (int*)(ws + 2 * H16 + 6400000);    // N+1 (padded 400128)
    int* bufs = (int*)(ws + 2 * H16 + 6400000 + 400128);
    _Float16* whi = (_Float16*)(ws + 2 * H16 + 6400000 + 2 * 400128);

    int* bcnt = bufs;                // NBUK
    int* bbase = bufs + 256;         // NBUK+1
    int* bcur = bufs + 512;          // NBUK
    unsigned* eb = (unsigned*)hH;    // E staged edges (hH written only later)

    hipMemsetAsync(bcnt, 0, NBUK * 4, stream);
    k_bhist<<<PGRID, 1024, 0, stream>>>(ei32, ei64, bcnt);
    k_bscan<<<1, 256, 0, stream>>>(bcnt, bbase, bcur);
    k_part<<<PGRID, 1024, 0, stream>>>(ei32, ei64, bcur, eb);
    k_bucket<<<NBUK, 1024, 0, stream>>>(eb, bbase, rp, ssrc);
    k_prepw<<<(6 * 16384 + 255) / 256, 256, 0, stream>>>(
        (const float*)d_in[2], (const float*)d_in[6], (const float*)d_in[8],
        (const float*)d_in[4], (const float*)d_in[9], (const float*)d_in[11], whi);

    dim3 g((NN + 127) / 128);
    int agrid = (NN + 3) / 4;
    // h1 = relu(x@W1.T+b1) -> fp16 hH
    k_gemm<false, false, true><<<g, 256, 0, stream>>>(
        x, whi + 0 * 16384, nullptr, nullptr, b1, hH);
    // conv1 mean-agg: hH -> aggH
    k_agg<<<agrid, 256, 0, stream>>>(hH, rp, ssrc, aggH);
    // fused conv1 + lin2: h3 in-place over aggH
    k_cfuse<<<g, 256, 0, stream>>>(
        aggH, hH, whi + 1 * 16384, whi + 2 * 16384, c1_bl,
        whi + 3 * 16384, b2, aggH);
    // conv2 mean-agg: aggH(h3) -> hH (h1 is dead)
    k_agg<<<agrid, 256, 0, stream>>>(aggH, rp, ssrc, hH);
    // conv2 dual GEMM -> f32 d_out
    k_gemm<true, true, false><<<g, 256, 0, stream>>>(
        hH, whi + 4 * 16384, aggH, whi + 5 * 16384, c2_bl, d_out);
}